// Round 1
// baseline (34.641 us; speedup 1.0000x reference)
//
#include <hip/hip_runtime.h>
#include <math.h>

#define NF 8
#define NA 14
#define D_CLAMP 10.0f
#define FAPE_EPS 1e-4f
#define ZINV (1.0f / 10.0f)

// ---------------------------------------------------------------------------
// Kernel 1: one block per frame. Computes sum_a flat_atom_mask[a] *
// min(sqrt(|Rp^T pp - Rt^T pt - (cp-ct)|^2 + eps), 10) and writes it to
// frame_sums[frame].
// ---------------------------------------------------------------------------
__global__ __launch_bounds__(256) void fape_frame_kernel(
    const float* __restrict__ predR,   // (b, N*NF, 3, 3)
    const float* __restrict__ predT,   // (b, N*NF, 3)
    const float* __restrict__ predPos, // (b, N*NA, 3)
    const float* __restrict__ atomMask,// (b, N*NA)
    const float* __restrict__ trueR,
    const float* __restrict__ trueT,
    const float* __restrict__ truePos,
    const float* __restrict__ seqMask, // (b, N)
    float* __restrict__ frameSums,     // (b*N*NF)
    int N)
{
    const int fg     = blockIdx.x;          // global frame id in [0, b*N*NF)
    const int framesPerBatch = N * NF;
    const int batch  = fg / framesPerBatch;
    const int nAtoms = N * NA;
    const int tid    = threadIdx.x;

    // Frame-uniform data (uniform addresses -> scalar loads via s_load)
    const float* Rp = predR + (size_t)fg * 9;
    const float* Rt = trueR + (size_t)fg * 9;
    const float* tp = predT + (size_t)fg * 3;
    const float* tt = trueT + (size_t)fg * 3;

    float rp[9], rt[9];
#pragma unroll
    for (int i = 0; i < 9; ++i) { rp[i] = Rp[i]; rt[i] = Rt[i]; }
    const float tp0 = tp[0], tp1 = tp[1], tp2 = tp[2];
    const float tt0 = tt[0], tt1 = tt[1], tt2 = tt[2];

    // c_i = (R^T t)_i = sum_j R[j*3+i] * t[j]; fold pred/true into one offset
    float off0 = (rp[0]*tp0 + rp[3]*tp1 + rp[6]*tp2) - (rt[0]*tt0 + rt[3]*tt1 + rt[6]*tt2);
    float off1 = (rp[1]*tp0 + rp[4]*tp1 + rp[7]*tp2) - (rt[1]*tt0 + rt[4]*tt1 + rt[7]*tt2);
    float off2 = (rp[2]*tp0 + rp[5]*tp1 + rp[8]*tp2) - (rt[2]*tt0 + rt[5]*tt1 + rt[8]*tt2);

    const float* pPos = predPos  + (size_t)batch * nAtoms * 3;
    const float* tPos = truePos  + (size_t)batch * nAtoms * 3;
    const float* aM   = atomMask + (size_t)batch * nAtoms;
    const float* sM   = seqMask  + (size_t)batch * N;

    float local = 0.0f;
    for (int a = tid; a < nAtoms; a += 256) {
        const float pp0 = pPos[3*a + 0], pp1 = pPos[3*a + 1], pp2 = pPos[3*a + 2];
        const float pt0 = tPos[3*a + 0], pt1 = tPos[3*a + 1], pt2 = tPos[3*a + 2];
        const float m   = aM[a] * sM[a / NA];

        float d0 = (rp[0]*pp0 + rp[3]*pp1 + rp[6]*pp2)
                 - (rt[0]*pt0 + rt[3]*pt1 + rt[6]*pt2) - off0;
        float d1 = (rp[1]*pp0 + rp[4]*pp1 + rp[7]*pp2)
                 - (rt[1]*pt0 + rt[4]*pt1 + rt[7]*pt2) - off1;
        float d2 = (rp[2]*pp0 + rp[5]*pp1 + rp[8]*pp2)
                 - (rt[2]*pt0 + rt[5]*pt1 + rt[8]*pt2) - off2;

        float dist = sqrtf(d0*d0 + d1*d1 + d2*d2 + FAPE_EPS);
        local += fminf(dist, D_CLAMP) * m;
    }

    // wave reduce (64 lanes), then cross-wave via LDS
#pragma unroll
    for (int o = 32; o > 0; o >>= 1) local += __shfl_down(local, o, 64);

    __shared__ float ws[4];
    const int wave = tid >> 6;
    if ((tid & 63) == 0) ws[wave] = local;
    __syncthreads();
    if (tid == 0) frameSums[fg] = ws[0] + ws[1] + ws[2] + ws[3];
}

// ---------------------------------------------------------------------------
// Kernel 2: one block per batch. Reduces frame sums with frame_mask, computes
// atom_count and frame_count, writes the final scalar.
// ---------------------------------------------------------------------------
__global__ __launch_bounds__(256) void fape_final_kernel(
    const float* __restrict__ frameSums,
    const float* __restrict__ atomMask,
    const float* __restrict__ seqMask,
    float* __restrict__ out,
    int N)
{
    const int batch  = blockIdx.x;
    const int tid    = threadIdx.x;
    const int nFrames = N * NF;
    const int nAtoms  = N * NA;

    const float* fS = frameSums + (size_t)batch * nFrames;
    const float* aM = atomMask  + (size_t)batch * nAtoms;
    const float* sM = seqMask   + (size_t)batch * N;

    float s = 0.0f, ac = 0.0f, fc = 0.0f;
    for (int f = tid; f < nFrames; f += 256) s  += fS[f] * sM[f / NF];
    for (int a = tid; a < nAtoms;  a += 256) ac += aM[a] * sM[a / NA];
    for (int n = tid; n < N;       n += 256) fc += sM[n];

#pragma unroll
    for (int o = 32; o > 0; o >>= 1) {
        s  += __shfl_down(s,  o, 64);
        ac += __shfl_down(ac, o, 64);
        fc += __shfl_down(fc, o, 64);
    }

    __shared__ float wsS[4], wsA[4], wsF[4];
    const int wave = tid >> 6;
    if ((tid & 63) == 0) { wsS[wave] = s; wsA[wave] = ac; wsF[wave] = fc; }
    __syncthreads();
    if (tid == 0) {
        const float S  = wsS[0] + wsS[1] + wsS[2] + wsS[3];
        const float AC = fmaxf(wsA[0] + wsA[1] + wsA[2] + wsA[3], 1.0f);
        const float FC = fmaxf((wsF[0] + wsF[1] + wsF[2] + wsF[3]) * (float)NF, 1.0f);
        out[batch] = S / AC / FC * ZINV;
    }
}

extern "C" void kernel_launch(void* const* d_in, const int* in_sizes, int n_in,
                              void* d_out, int out_size, void* d_ws, size_t ws_size,
                              hipStream_t stream) {
    const float* predR   = (const float*)d_in[0];
    const float* predT   = (const float*)d_in[1];
    const float* predPos = (const float*)d_in[2];
    const float* atomM   = (const float*)d_in[3];
    const float* trueR   = (const float*)d_in[4];
    const float* trueT   = (const float*)d_in[5];
    const float* truePos = (const float*)d_in[6];
    const float* seqM    = (const float*)d_in[7];
    float* out = (float*)d_out;

    const int b = out_size;                 // fape_loss has shape (b,)
    const int N = in_sizes[7] / b;          // seq_mask is (b, N)
    const int nFrames = b * N * NF;

    float* frameSums = (float*)d_ws;        // b*N*NF floats

    fape_frame_kernel<<<nFrames, 256, 0, stream>>>(
        predR, predT, predPos, atomM, trueR, trueT, truePos, seqM,
        frameSums, N);
    fape_final_kernel<<<b, 256, 0, stream>>>(frameSums, atomM, seqM, out, N);
}

// Round 2
// 27.606 us; speedup vs baseline: 1.2548x; 1.2548x over previous
//
#include <hip/hip_runtime.h>

#define NF 8
#define NA 14
#define FT 4      // frames per block (must divide NF)
#define SPLIT 2   // atom-range splits per frame group
#define D_CLAMP 10.0f
#define FAPE_EPS 1e-4f
#define ZINV (1.0f / 10.0f)

// ---------------------------------------------------------------------------
// Kernel 1: each block handles FT consecutive frames x one atom-range slice.
// One atom load feeds FT frames (4x less L1/L2 traffic, amortized addressing).
// Writes partial sums to ws: partial[sp][globalFrame].
// ---------------------------------------------------------------------------
__global__ __launch_bounds__(256, 3) void fape_frame_kernel(
    const float* __restrict__ predR,   // (b, N*NF, 3, 3)
    const float* __restrict__ predT,   // (b, N*NF, 3)
    const float* __restrict__ predPos, // (b, N*NA, 3)
    const float* __restrict__ atomMask,// (b, N*NA)
    const float* __restrict__ trueR,
    const float* __restrict__ trueT,
    const float* __restrict__ truePos,
    const float* __restrict__ seqMask, // (b, N)
    float* __restrict__ partial,       // (SPLIT, b*N*NF)
    int N, int totalFrames)
{
    const int nFramesPB = N * NF;
    const int fgrp = blockIdx.x / SPLIT;
    const int sp   = blockIdx.x % SPLIT;
    const int fg0  = fgrp * FT;             // first global frame id (batch-aligned: FT|NF)
    const int batch = fg0 / nFramesPB;
    const int nAtoms = N * NA;
    const int tid = threadIdx.x;

    // Frame-uniform constants (blockIdx-derived addresses -> scalar loads)
    float rp[FT][9], rt[FT][9], off[FT][3];
#pragma unroll
    for (int k = 0; k < FT; ++k) {
        const float* Rp = predR + (size_t)(fg0 + k) * 9;
        const float* Rt = trueR + (size_t)(fg0 + k) * 9;
        const float* tp = predT + (size_t)(fg0 + k) * 3;
        const float* tt = trueT + (size_t)(fg0 + k) * 3;
#pragma unroll
        for (int i = 0; i < 9; ++i) { rp[k][i] = Rp[i]; rt[k][i] = Rt[i]; }
        const float tp0 = tp[0], tp1 = tp[1], tp2 = tp[2];
        const float tt0 = tt[0], tt1 = tt[1], tt2 = tt[2];
#pragma unroll
        for (int i = 0; i < 3; ++i) {
            off[k][i] = (rp[k][i]*tp0 + rp[k][3+i]*tp1 + rp[k][6+i]*tp2)
                      - (rt[k][i]*tt0 + rt[k][3+i]*tt1 + rt[k][6+i]*tt2);
        }
    }

    const float* pPos = predPos  + (size_t)batch * nAtoms * 3;
    const float* tPos = truePos  + (size_t)batch * nAtoms * 3;
    const float* aM   = atomMask + (size_t)batch * nAtoms;
    const float* sM   = seqMask  + (size_t)batch * N;

    // Contiguous atom slice for this split
    const int aBeg = (nAtoms * sp) / SPLIT;
    const int aEnd = (nAtoms * (sp + 1)) / SPLIT;

    float acc[FT];
#pragma unroll
    for (int k = 0; k < FT; ++k) acc[k] = 0.0f;

    for (int a = aBeg + tid; a < aEnd; a += 256) {
        const float pp0 = pPos[3*a + 0], pp1 = pPos[3*a + 1], pp2 = pPos[3*a + 2];
        const float pt0 = tPos[3*a + 0], pt1 = tPos[3*a + 1], pt2 = tPos[3*a + 2];
        const float m   = aM[a] * sM[a / NA];

#pragma unroll
        for (int k = 0; k < FT; ++k) {
            float d0 = (rp[k][0]*pp0 + rp[k][3]*pp1 + rp[k][6]*pp2)
                     - (rt[k][0]*pt0 + rt[k][3]*pt1 + rt[k][6]*pt2) - off[k][0];
            float d1 = (rp[k][1]*pp0 + rp[k][4]*pp1 + rp[k][7]*pp2)
                     - (rt[k][1]*pt0 + rt[k][4]*pt1 + rt[k][7]*pt2) - off[k][1];
            float d2 = (rp[k][2]*pp0 + rp[k][5]*pp1 + rp[k][8]*pp2)
                     - (rt[k][2]*pt0 + rt[k][5]*pt1 + rt[k][8]*pt2) - off[k][2];
            float dist = __builtin_amdgcn_sqrtf(d0*d0 + d1*d1 + d2*d2 + FAPE_EPS);
            acc[k] += fminf(dist, D_CLAMP) * m;
        }
    }

    // wave reduce each accumulator, then cross-wave via LDS
#pragma unroll
    for (int k = 0; k < FT; ++k) {
#pragma unroll
        for (int o = 32; o > 0; o >>= 1) acc[k] += __shfl_down(acc[k], o, 64);
    }

    __shared__ float ws[4][FT];
    const int wave = tid >> 6;
    if ((tid & 63) == 0) {
#pragma unroll
        for (int k = 0; k < FT; ++k) ws[wave][k] = acc[k];
    }
    __syncthreads();
    if (tid < FT) {
        const float s = ws[0][tid] + ws[1][tid] + ws[2][tid] + ws[3][tid];
        partial[(size_t)sp * totalFrames + fg0 + tid] = s;
    }
}

// ---------------------------------------------------------------------------
// Kernel 2: one block per batch. Reduces partial frame sums with frame_mask,
// computes atom_count and frame_count, writes the final scalar.
// ---------------------------------------------------------------------------
__global__ __launch_bounds__(256) void fape_final_kernel(
    const float* __restrict__ partial,
    const float* __restrict__ atomMask,
    const float* __restrict__ seqMask,
    float* __restrict__ out,
    int N, int totalFrames)
{
    const int batch  = blockIdx.x;
    const int tid    = threadIdx.x;
    const int nFrames = N * NF;
    const int nAtoms  = N * NA;

    const float* aM = atomMask + (size_t)batch * nAtoms;
    const float* sM = seqMask  + (size_t)batch * N;

    float s = 0.0f, ac = 0.0f, fc = 0.0f;
    for (int f = tid; f < nFrames; f += 256) {
        float v = 0.0f;
#pragma unroll
        for (int sp = 0; sp < SPLIT; ++sp)
            v += partial[(size_t)sp * totalFrames + (size_t)batch * nFrames + f];
        s += v * sM[f / NF];
    }
    for (int a = tid; a < nAtoms;  a += 256) ac += aM[a] * sM[a / NA];
    for (int n = tid; n < N;       n += 256) fc += sM[n];

#pragma unroll
    for (int o = 32; o > 0; o >>= 1) {
        s  += __shfl_down(s,  o, 64);
        ac += __shfl_down(ac, o, 64);
        fc += __shfl_down(fc, o, 64);
    }

    __shared__ float wsS[4], wsA[4], wsF[4];
    const int wave = tid >> 6;
    if ((tid & 63) == 0) { wsS[wave] = s; wsA[wave] = ac; wsF[wave] = fc; }
    __syncthreads();
    if (tid == 0) {
        const float S  = wsS[0] + wsS[1] + wsS[2] + wsS[3];
        const float AC = fmaxf(wsA[0] + wsA[1] + wsA[2] + wsA[3], 1.0f);
        const float FC = fmaxf((wsF[0] + wsF[1] + wsF[2] + wsF[3]) * (float)NF, 1.0f);
        out[batch] = S / AC / FC * ZINV;
    }
}

extern "C" void kernel_launch(void* const* d_in, const int* in_sizes, int n_in,
                              void* d_out, int out_size, void* d_ws, size_t ws_size,
                              hipStream_t stream) {
    const float* predR   = (const float*)d_in[0];
    const float* predT   = (const float*)d_in[1];
    const float* predPos = (const float*)d_in[2];
    const float* atomM   = (const float*)d_in[3];
    const float* trueR   = (const float*)d_in[4];
    const float* trueT   = (const float*)d_in[5];
    const float* truePos = (const float*)d_in[6];
    const float* seqM    = (const float*)d_in[7];
    float* out = (float*)d_out;

    const int b = out_size;                 // fape_loss has shape (b,)
    const int N = in_sizes[7] / b;          // seq_mask is (b, N)
    const int totalFrames = b * N * NF;

    float* partial = (float*)d_ws;          // SPLIT * totalFrames floats

    const int grid1 = (totalFrames / FT) * SPLIT;
    fape_frame_kernel<<<grid1, 256, 0, stream>>>(
        predR, predT, predPos, atomM, trueR, trueT, truePos, seqM,
        partial, N, totalFrames);
    fape_final_kernel<<<b, 256, 0, stream>>>(partial, atomM, seqM, out, N, totalFrames);
}